// Round 3
// baseline (2599.324 us; speedup 1.0000x reference)
//
#include <hip/hip_runtime.h>
#include <math.h>

#define B_  2
#define S_  1024
#define H_  4096
#define NH_ 32
#define HD_ 128
#define I_  11008
#define R_  2048   // B*S tokens

typedef __attribute__((ext_vector_type(4))) int i32x4;
typedef __attribute__((ext_vector_type(4))) float f32x4;
typedef __attribute__((ext_vector_type(8))) short bf16x8;

// ---------------------------------------------------------------------------
// async global->LDS, 16B per lane. LDS dest is wave-uniform base (+lane*16 by HW).
__device__ __forceinline__ void gload_lds16(const void* g, void* l) {
    __builtin_amdgcn_global_load_lds(
        (const __attribute__((address_space(1))) unsigned int*)g,
        (__attribute__((address_space(3))) unsigned int*)l, 16, 0, 0);
}

__device__ __forceinline__ unsigned short f2bf(float f) {
    unsigned int u = __float_as_uint(f);
    u += 0x7fffu + ((u >> 16) & 1u);   // RNE
    return (unsigned short)(u >> 16);
}

// ---------------------------------------------------------------------------
// RMSNorm + per-tensor symmetric int8 quant (scale folded into w).
__global__ __launch_bounds__(256)
void rmsnorm_quant_k(const float* __restrict__ x, const float* __restrict__ w,
                     signed char* __restrict__ out)
{
    __shared__ float red[4];
    const int tid = threadIdx.x;
    const long row = blockIdx.x;
    const float4* xr = (const float4*)(x + row * H_);
    float4 xv[4];
    float ss = 0.f;
#pragma unroll
    for (int i = 0; i < 4; ++i) {
        xv[i] = xr[tid + i * 256];
        ss += xv[i].x * xv[i].x + xv[i].y * xv[i].y
            + xv[i].z * xv[i].z + xv[i].w * xv[i].w;
    }
#pragma unroll
    for (int off = 32; off; off >>= 1) ss += __shfl_xor(ss, off);
    if ((tid & 63) == 0) red[tid >> 6] = ss;
    __syncthreads();
    const float tot = red[0] + red[1] + red[2] + red[3];
    const float sc = 1.f / sqrtf(tot * (1.f / (float)H_) + 1e-6f);
    const float4* wr = (const float4*)w;
    int* outi = (int*)(out + row * H_);
#pragma unroll
    for (int i = 0; i < 4; ++i) {
        const float4 wv = wr[tid + i * 256];
        const int b0 = (int)fminf(fmaxf(rintf(xv[i].x * sc * wv.x), -128.f), 127.f);
        const int b1 = (int)fminf(fmaxf(rintf(xv[i].y * sc * wv.y), -128.f), 127.f);
        const int b2 = (int)fminf(fmaxf(rintf(xv[i].z * sc * wv.z), -128.f), 127.f);
        const int b3 = (int)fminf(fmaxf(rintf(xv[i].w * sc * wv.w), -128.f), 127.f);
        outi[tid + i * 256] = (b0 & 255) | ((b1 & 255) << 8) | ((b2 & 255) << 16) | (b3 << 24);
    }
}

// ---------------------------------------------------------------------------
// int8 GEMM: C[M,N] = f32(A[M,K]i8 . W[N,K]i8^T) * scale + bias (+ residual)
// 2-phase double-buffered pipeline: issue next-tile loads early (T14), one
// barrier per K-step. 1-D grid with bijective XCD-chunked remap (T1) so
// row-blocks sharing a W panel share an XCD L2.
__global__ __launch_bounds__(256, 3)
void gemm_i8(const signed char* __restrict__ A, const int* __restrict__ W,
             const float* __restrict__ scale_ptr, const float* __restrict__ bias,
             const float* __restrict__ residual, float* __restrict__ C,
             const int N, const int K, const int gx)
{
    __shared__ __align__(16) signed char lsA[2][8192];
    __shared__ __align__(16) signed char lsB[2][8192];

    // bijective XCD chunked remap (m204): chunk c has q+1 blocks if c<r else q
    int bid = blockIdx.x;
    {
        const int nwg = gridDim.x;
        const int q = nwg >> 3, r = nwg & 7;
        const int xcd = bid & 7, idx = bid >> 3;
        bid = (xcd < r) ? (xcd * (q + 1) + idx)
                        : (r * (q + 1) + (xcd - r) * q + idx);
    }
    const int bx = bid % gx, by = bid / gx;     // row-block fastest in chunk

    const int tid  = threadIdx.x;
    const int lane = tid & 63, wid = tid >> 6;
    const int bm = bx << 7, bn = by << 7;
    const int wm = (wid >> 1) << 6, wn = (wid & 1) << 6;

    i32x4 acc[4][4];
#pragma unroll
    for (int m = 0; m < 4; ++m)
#pragma unroll
        for (int n = 0; n < 4; ++n) acc[m][n] = (i32x4){0, 0, 0, 0};

    const int brow = tid >> 1;
    const int bkh  = tid & 1;
    const long wrow = (long)(bn + brow) * K + bkh * 32;
    const long arow0 = (long)(bm + ((wid    ) & 1) * 64 + lane) * K + ((wid    ) >> 1) * 16;
    const long arow1 = (long)(bm + ((wid + 4) & 1) * 64 + lane) * K + ((wid + 4) >> 1) * 16;

    int4 wreg[8];

    // ---- prologue: stage tile 0 into buffer 0 ----
    {
        const int4* gw = (const int4*)(W + wrow);
#pragma unroll
        for (int i = 0; i < 8; ++i) wreg[i] = gw[i];
        gload_lds16(A + arow0, lsA[0] + (wid    ) * 1024);
        gload_lds16(A + arow1, lsA[0] + (wid + 4) * 1024);
        int p[8];
#pragma unroll
        for (int i = 0; i < 8; ++i) {
            const int4 w4 = wreg[i];
            p[i] = (w4.x & 255) | ((w4.y & 255) << 8) | ((w4.z & 255) << 16) | (w4.w << 24);
        }
        *(i32x4*)(lsB[0] + (bkh * 2 + 0) * 2048 + brow * 16) = (i32x4){p[0], p[1], p[2], p[3]};
        *(i32x4*)(lsB[0] + (bkh * 2 + 1) * 2048 + brow * 16) = (i32x4){p[4], p[5], p[6], p[7]};
    }
    __syncthreads();

    const int nk = K >> 6;
    int cur = 0;
    for (int kt = 0; kt < nk; ++kt) {
        const int nxt = cur ^ 1;
        const bool pf = (kt + 1 < nk);
        if (pf) {
            const int k0 = (kt + 1) << 6;
            const int4* gw = (const int4*)(W + wrow + k0);
#pragma unroll
            for (int i = 0; i < 8; ++i) wreg[i] = gw[i];
            gload_lds16(A + arow0 + k0, lsA[nxt] + (wid    ) * 1024);
            gload_lds16(A + arow1 + k0, lsA[nxt] + (wid + 4) * 1024);
        }

        const int kg = (lane >> 4) * 2048, fr = (lane & 15) * 16;
        i32x4 af[4], bf[4];
#pragma unroll
        for (int m = 0; m < 4; ++m)
            af[m] = *(const i32x4*)(lsA[cur] + kg + wm * 16 + m * 256 + fr);
#pragma unroll
        for (int n = 0; n < 4; ++n)
            bf[n] = *(const i32x4*)(lsB[cur] + kg + wn * 16 + n * 256 + fr);
#pragma unroll
        for (int m = 0; m < 4; ++m)
#pragma unroll
            for (int n = 0; n < 4; ++n)
                acc[m][n] = __builtin_amdgcn_mfma_i32_16x16x64_i8(af[m], bf[n], acc[m][n], 0, 0, 0);

        if (pf) {   // pack + ds_write after MFMAs: W load latency hid under compute
            int p[8];
#pragma unroll
            for (int i = 0; i < 8; ++i) {
                const int4 w4 = wreg[i];
                p[i] = (w4.x & 255) | ((w4.y & 255) << 8) | ((w4.z & 255) << 16) | (w4.w << 24);
            }
            *(i32x4*)(lsB[nxt] + (bkh * 2 + 0) * 2048 + brow * 16) = (i32x4){p[0], p[1], p[2], p[3]};
            *(i32x4*)(lsB[nxt] + (bkh * 2 + 1) * 2048 + brow * 16) = (i32x4){p[4], p[5], p[6], p[7]};
        }
        __syncthreads();
        cur = nxt;
    }

    const float s = *scale_ptr;
    const int rq = (lane >> 4) * 4, fc = lane & 15;
#pragma unroll
    for (int m = 0; m < 4; ++m) {
#pragma unroll
        for (int n = 0; n < 4; ++n) {
            const int col = bn + wn + n * 16 + fc;
            const float bcol = bias[col];
#pragma unroll
            for (int r = 0; r < 4; ++r) {
                const int row = bm + wm + m * 16 + rq + r;
                float v = (float)acc[m][n][r] * s + bcol;
                if (residual) v += residual[(long)row * N + col];
                C[(long)row * N + col] = v;
            }
        }
    }
}

// ---------------------------------------------------------------------------
// RoPE applied in-place to q and k, layout [B,S,NH,HD] == [B,S,H] h-major.
__global__ __launch_bounds__(256)
void rope_k(float* __restrict__ q, float* __restrict__ k)
{
    const int row = blockIdx.x;            // token index b*S+s
    const int s = row & (S_ - 1);
    float* qr = q + (long)row * H_;
    float* kr = k + (long)row * H_;
    for (int t = threadIdx.x; t < NH_ * 64; t += 256) {
        const int nh = t >> 6, i = t & 63;
        const float inv = powf(10000.f, -(float)(2 * i) * (1.f / 128.f));
        const float f = (float)s * inv;
        float sn, c;
        sincosf(f, &sn, &c);
        const int base = nh * 128 + i;
        const float q0 = qr[base], q1 = qr[base + 64];
        qr[base]      = q0 * c - q1 * sn;
        qr[base + 64] = q1 * c + q0 * sn;
        const float k0 = kr[base], k1 = kr[base + 64];
        kr[base]      = k0 * c - k1 * sn;
        kr[base + 64] = k1 * c + k0 * sn;
    }
}

// ---------------------------------------------------------------------------
// Flash attention, bf16 MFMA (16x16x32), fp32 online softmax.
__global__ __launch_bounds__(256, 2)
void attn_mfma_k(const float* __restrict__ q, const float* __restrict__ k,
                 const float* __restrict__ v, float* __restrict__ o)
{
    __shared__ __align__(16) char lsK[8192];        // [32 krow][128 d] bf16, XOR swizzle
    __shared__ __align__(16) char lsV[10240];       // V^T [128 d][40 pitch] bf16
    __shared__ __align__(16) char lsP[4][1024];     // per-wave P [16][32] bf16, XOR swizzle

    const int tid = threadIdx.x, lane = tid & 63, wid = tid >> 6;
    const int bid = blockIdx.x;
    const int qt = 15 - (bid >> 6);                 // reversed: long blocks first
    const int bh = bid & 63;
    const int b = bh >> 5, h = bh & 31;
    const int q0 = qt * 64;
    const int qw = q0 + wid * 16;                   // this wave's first q row

    const float* qbase = q + (long)(b * S_) * H_ + (long)h * HD_;
    const float* kbase = k + (long)(b * S_) * H_ + (long)h * HD_;
    const float* vbase = v + (long)(b * S_) * H_ + (long)h * HD_;

    const int frow = lane & 15, fgrp = lane >> 4;
    const float sc = 0.08838834764831845f;          // 1/sqrt(128), folded into Q

    bf16x8 qf[4];
    {
        const float* qr = qbase + (long)(qw + frow) * H_;
#pragma unroll
        for (int c = 0; c < 4; ++c) {
            const float4 a = *(const float4*)(qr + c * 32 + fgrp * 8);
            const float4 bq = *(const float4*)(qr + c * 32 + fgrp * 8 + 4);
            bf16x8 t;
            t[0] = (short)f2bf(a.x * sc);  t[1] = (short)f2bf(a.y * sc);
            t[2] = (short)f2bf(a.z * sc);  t[3] = (short)f2bf(a.w * sc);
            t[4] = (short)f2bf(bq.x * sc); t[5] = (short)f2bf(bq.y * sc);
            t[6] = (short)f2bf(bq.z * sc); t[7] = (short)f2bf(bq.w * sc);
            qf[c] = t;
        }
    }

    f32x4 oacc[8];
#pragma unroll
    for (int n2 = 0; n2 < 8; ++n2) oacc[n2] = (f32x4){0.f, 0.f, 0.f, 0.f};
    float mr[4] = {-1e30f, -1e30f, -1e30f, -1e30f};
    float lr[4] = {0.f, 0.f, 0.f, 0.f};

    const int nt = (q0 >> 5) + 2;
    for (int kt = 0; kt < nt; ++kt) {
        if (kt) __syncthreads();
        {
            const float* kg = kbase + (long)(kt * 32) * H_;
            const float* vg = vbase + (long)(kt * 32) * H_;
#pragma unroll
            for (int i = 0; i < 4; ++i) {
                const int lin = i * 256 + tid;
                const int kr = lin >> 5;
                const int d4 = (lin & 31) * 4;
                const float4 kv = *(const float4*)(kg + (long)kr * H_ + d4);
                const float4 vv = *(const float4*)(vg + (long)kr * H_ + d4);
                ushort4 kb;
                kb.x = f2bf(kv.x); kb.y = f2bf(kv.y); kb.z = f2bf(kv.z); kb.w = f2bf(kv.w);
                *(ushort4*)(lsK + kr * 256 + ((d4 * 2) ^ ((kr & 7) << 4))) = kb;
                *(unsigned short*)(lsV + (d4 + 0) * 80 + kr * 2) = f2bf(vv.x);
                *(unsigned short*)(lsV + (d4 + 1) * 80 + kr * 2) = f2bf(vv.y);
                *(unsigned short*)(lsV + (d4 + 2) * 80 + kr * 2) = f2bf(vv.z);
                *(unsigned short*)(lsV + (d4 + 3) * 80 + kr * 2) = f2bf(vv.w);
            }
        }
        __syncthreads();

        if (kt * 32 <= qw + 15) {
            f32x4 s0 = (f32x4){0.f, 0.f, 0.f, 0.f};
            f32x4 s1 = (f32x4){0.f, 0.f, 0.f, 0.f};
            const int swz = (frow & 7) << 4;
#pragma unroll
            for (int c = 0; c < 4; ++c) {
                const int dby = c * 64 + fgrp * 16;
                const bf16x8 kfA = *(const bf16x8*)(lsK + frow * 256 + (dby ^ swz));
                const bf16x8 kfB = *(const bf16x8*)(lsK + (frow + 16) * 256 + (dby ^ swz));
                s0 = __builtin_amdgcn_mfma_f32_16x16x32_bf16(qf[c], kfA, s0, 0, 0, 0);
                s1 = __builtin_amdgcn_mfma_f32_16x16x32_bf16(qf[c], kfB, s1, 0, 0, 0);
            }

            const int colg0 = kt * 32 + frow;
            float cf[4];
#pragma unroll
            for (int r = 0; r < 4; ++r) {
                const int rowg = qw + fgrp * 4 + r;
                const float a0 = (colg0 <= rowg) ? s0[r] : -1e30f;
                const float a1 = (colg0 + 16 <= rowg) ? s1[r] : -1e30f;
                float mx = fmaxf(a0, a1);
#pragma unroll
                for (int off2 = 1; off2 < 16; off2 <<= 1) mx = fmaxf(mx, __shfl_xor(mx, off2));
                const float mnew = fmaxf(mr[r], mx);
                cf[r] = __expf(mr[r] - mnew);
                mr[r] = mnew;
                const float p0 = __expf(a0 - mnew);
                const float p1 = __expf(a1 - mnew);
                float sm = p0 + p1;
#pragma unroll
                for (int off2 = 1; off2 < 16; off2 <<= 1) sm += __shfl_xor(sm, off2);
                lr[r] = lr[r] * cf[r] + sm;
                const int row = fgrp * 4 + r;
                const int psw = (row & 3) << 4;
                *(unsigned short*)(lsP[wid] + row * 64 + ((frow * 2) ^ psw)) = f2bf(p0);
                *(unsigned short*)(lsP[wid] + row * 64 + (((16 + frow) * 2) ^ psw)) = f2bf(p1);
            }
#pragma unroll
            for (int n2 = 0; n2 < 8; ++n2) {
#pragma unroll
                for (int r = 0; r < 4; ++r) oacc[n2][r] *= cf[r];
            }
            const bf16x8 pf = *(const bf16x8*)(lsP[wid] + frow * 64 + ((fgrp * 16) ^ ((frow & 3) << 4)));
#pragma unroll
            for (int n2 = 0; n2 < 8; ++n2) {
                const bf16x8 vf = *(const bf16x8*)(lsV + (n2 * 16 + frow) * 80 + fgrp * 16);
                oacc[n2] = __builtin_amdgcn_mfma_f32_16x16x32_bf16(pf, vf, oacc[n2], 0, 0, 0);
            }
        }
    }

    float inv[4];
#pragma unroll
    for (int r = 0; r < 4; ++r) inv[r] = 1.f / lr[r];
    float* ob = o + (long)(b * S_) * H_ + (long)h * HD_;
#pragma unroll
    for (int n2 = 0; n2 < 8; ++n2) {
#pragma unroll
        for (int r = 0; r < 4; ++r) {
            ob[(long)(qw + fgrp * 4 + r) * H_ + n2 * 16 + frow] = oacc[n2][r] * inv[r];
        }
    }
}

// ---------------------------------------------------------------------------
__global__ __launch_bounds__(256)
void quant_k(const float* __restrict__ x, const float* __restrict__ sp,
             signed char* __restrict__ out, const long n4)
{
    const float inv = 1.f / sp[0];
    const long i0 = (long)blockIdx.x * 256 + threadIdx.x;
    const long step = (long)gridDim.x * 256;
    for (long i = i0; i < n4; i += step) {
        const float4 xv = ((const float4*)x)[i];
        const int b0 = (int)fminf(fmaxf(rintf(xv.x * inv), -128.f), 127.f);
        const int b1 = (int)fminf(fmaxf(rintf(xv.y * inv), -128.f), 127.f);
        const int b2 = (int)fminf(fmaxf(rintf(xv.z * inv), -128.f), 127.f);
        const int b3 = (int)fminf(fmaxf(rintf(xv.w * inv), -128.f), 127.f);
        ((int*)out)[i] = (b0 & 255) | ((b1 & 255) << 8) | ((b2 & 255) << 16) | (b3 << 24);
    }
}

__global__ __launch_bounds__(256)
void silu_mul_quant_k(const float* __restrict__ g, const float* __restrict__ u,
                      const float* __restrict__ sp, signed char* __restrict__ out,
                      const long n4)
{
    const float inv = 1.f / sp[0];
    const long i0 = (long)blockIdx.x * 256 + threadIdx.x;
    const long step = (long)gridDim.x * 256;
    for (long i = i0; i < n4; i += step) {
        const float4 gv = ((const float4*)g)[i];
        const float4 uv = ((const float4*)u)[i];
        const float a0 = gv.x / (1.f + __expf(-gv.x)) * uv.x;
        const float a1 = gv.y / (1.f + __expf(-gv.y)) * uv.y;
        const float a2 = gv.z / (1.f + __expf(-gv.z)) * uv.z;
        const float a3 = gv.w / (1.f + __expf(-gv.w)) * uv.w;
        const int b0 = (int)fminf(fmaxf(rintf(a0 * inv), -128.f), 127.f);
        const int b1 = (int)fminf(fmaxf(rintf(a1 * inv), -128.f), 127.f);
        const int b2 = (int)fminf(fmaxf(rintf(a2 * inv), -128.f), 127.f);
        const int b3 = (int)fminf(fmaxf(rintf(a3 * inv), -128.f), 127.f);
        ((int*)out)[i] = (b0 & 255) | ((b1 & 255) << 8) | ((b2 & 255) << 16) | (b3 << 24);
    }
}

// ---------------------------------------------------------------------------
extern "C" void kernel_launch(void* const* d_in, const int* in_sizes, int n_in,
                              void* d_out, int out_size, void* d_ws, size_t ws_size,
                              hipStream_t stream)
{
    const float* hidden = (const float*)d_in[0];
    const float* ln1 = (const float*)d_in[1];
    const float* ln2 = (const float*)d_in[2];
    const int* Wq = (const int*)d_in[3];
    const int* Wk = (const int*)d_in[4];
    const int* Wv = (const int*)d_in[5];
    const int* Wo = (const int*)d_in[6];
    const int* Wg = (const int*)d_in[7];
    const int* Wu = (const int*)d_in[8];
    const int* Wd = (const int*)d_in[9];
    const float* bq = (const float*)d_in[10];
    const float* bk = (const float*)d_in[11];
    const float* bv = (const float*)d_in[12];
    const float* bo = (const float*)d_in[13];
    const float* bg = (const float*)d_in[14];
    const float* bu = (const float*)d_in[15];
    const float* bd = (const float*)d_in[16];
    const float* sq = (const float*)d_in[17];
    const float* sk = (const float*)d_in[18];
    const float* sv = (const float*)d_in[19];
    const float* so = (const float*)d_in[20];
    const float* sg = (const float*)d_in[21];
    const float* su = (const float*)d_in[22];
    const float* sd = (const float*)d_in[23];
    const float* o_sc = (const float*)d_in[24];
    const float* d_sc = (const float*)d_in[25];

    char* ws = (char*)d_ws;
    signed char* HQ = (signed char*)ws;
    signed char* AQ = (signed char*)ws;
    float* Qb = (float*)(ws + ((size_t)32 << 20));
    float* Kb = (float*)(ws + ((size_t)64 << 20));
    float* Vb = (float*)(ws + ((size_t)96 << 20));
    float* Gb = (float*)(ws + ((size_t)64 << 20));
    float* Ub = (float*)(ws + ((size_t)150 << 20));
    float* Hb = Qb;
    float* out = (float*)d_out;

    const dim3 blk(256);
    const int gxH = R_ / 128;                 // 16 row blocks
    const int nwgH = gxH * (H_ / 128);        // 512
    const int nwgI = gxH * (I_ / 128);        // 1376

    rmsnorm_quant_k<<<R_, blk, 0, stream>>>(hidden, ln1, HQ);
    gemm_i8<<<nwgH, blk, 0, stream>>>(HQ, Wq, sq, bq, nullptr, Qb, H_, H_, gxH);
    gemm_i8<<<nwgH, blk, 0, stream>>>(HQ, Wk, sk, bk, nullptr, Kb, H_, H_, gxH);
    gemm_i8<<<nwgH, blk, 0, stream>>>(HQ, Wv, sv, bv, nullptr, Vb, H_, H_, gxH);
    rope_k<<<R_, blk, 0, stream>>>(Qb, Kb);
    attn_mfma_k<<<B_ * NH_ * (S_ / 64), blk, 0, stream>>>(Qb, Kb, Vb, Qb);
    quant_k<<<2048, blk, 0, stream>>>(Qb, o_sc, HQ, (long)R_ * H_ / 4);
    gemm_i8<<<nwgH, blk, 0, stream>>>(HQ, Wo, so, bo, hidden, Hb, H_, H_, gxH);
    rmsnorm_quant_k<<<R_, blk, 0, stream>>>(Hb, ln2, HQ);
    gemm_i8<<<nwgI, blk, 0, stream>>>(HQ, Wg, sg, bg, nullptr, Gb, I_, H_, gxH);
    gemm_i8<<<nwgI, blk, 0, stream>>>(HQ, Wu, su, bu, nullptr, Ub, I_, H_, gxH);
    silu_mul_quant_k<<<2048, blk, 0, stream>>>(Gb, Ub, d_sc, AQ, (long)R_ * I_ / 4);
    gemm_i8<<<nwgH, blk, 0, stream>>>(AQ, Wd, sd, bd, Hb, out, H_, I_, gxH);
}

// Round 4
// 1003.837 us; speedup vs baseline: 2.5894x; 2.5894x over previous
//
#include <hip/hip_runtime.h>
#include <math.h>

#define B_  2
#define S_  1024
#define H_  4096
#define NH_ 32
#define HD_ 128
#define I_  11008
#define R_  2048   // B*S tokens

typedef __attribute__((ext_vector_type(4))) int i32x4;
typedef __attribute__((ext_vector_type(4))) float f32x4;
typedef __attribute__((ext_vector_type(8))) short bf16x8;

// Tiled int8 activation/weight layout ("tile image"): for matrix [Rows][K],
// nk = K/64; tile (rb, kt) is 8192 B at ((rb*nk + kt)<<13), internally
// [kgrp 0..3][row 0..127][16B]  (kgrp = (k%64)/16). This is exactly the LDS
// image the MFMA fragment reads expect -> staging is contiguous 1KB chunks.

// ---------------------------------------------------------------------------
__device__ __forceinline__ void gload_lds16(const void* g, void* l) {
    __builtin_amdgcn_global_load_lds(
        (const __attribute__((address_space(1))) unsigned int*)g,
        (__attribute__((address_space(3))) unsigned int*)l, 16, 0, 0);
}

__device__ __forceinline__ unsigned short f2bf(float f) {
    unsigned int u = __float_as_uint(f);
    u += 0x7fffu + ((u >> 16) & 1u);   // RNE
    return (unsigned short)(u >> 16);
}

// ---------------------------------------------------------------------------
// Pack one W (int32 [N][K]) into tiled-i8. Grid: (nk, N/128).
__global__ __launch_bounds__(256)
void packW_k(const int* __restrict__ W, signed char* __restrict__ out, const int K)
{
    const int kt = blockIdx.x, cb = blockIdx.y, nk = gridDim.x;
    const int t = threadIdx.x;
    int* otile = (int*)(out + ((long)(cb * nk + kt) << 13));
#pragma unroll
    for (int i = 0; i < 8; ++i) {
        const int o = i * 256 + t;                 // int32 index in tile
        const int g = o >> 9, r = (o >> 2) & 127, jj = o & 3;
        const int4 w4 = *(const int4*)(W + (long)(cb * 128 + r) * K + kt * 64 + g * 16 + jj * 4);
        otile[o] = (w4.x & 255) | ((w4.y & 255) << 8) | ((w4.z & 255) << 16) | (w4.w << 24);
    }
}

// ---------------------------------------------------------------------------
// RMSNorm + int8 quant (scale folded into w). Output in tiled-i8 (nk=64).
__global__ __launch_bounds__(256)
void rmsnorm_quant_k(const float* __restrict__ x, const float* __restrict__ w,
                     signed char* __restrict__ out)
{
    __shared__ float red[4];
    const int tid = threadIdx.x;
    const long row = blockIdx.x;
    const float4* xr = (const float4*)(x + row * H_);
    float4 xv[4];
    float ss = 0.f;
#pragma unroll
    for (int i = 0; i < 4; ++i) {
        xv[i] = xr[tid + i * 256];
        ss += xv[i].x * xv[i].x + xv[i].y * xv[i].y
            + xv[i].z * xv[i].z + xv[i].w * xv[i].w;
    }
#pragma unroll
    for (int off = 32; off; off >>= 1) ss += __shfl_xor(ss, off);
    if ((tid & 63) == 0) red[tid >> 6] = ss;
    __syncthreads();
    const float tot = red[0] + red[1] + red[2] + red[3];
    const float sc = 1.f / sqrtf(tot * (1.f / (float)H_) + 1e-6f);
    const float4* wr = (const float4*)w;
    int* ob = (int*)out;
    const long rb = row >> 7;
    const int rr = (int)(row & 127);
#pragma unroll
    for (int i = 0; i < 4; ++i) {
        const float4 wv = wr[tid + i * 256];
        const int b0 = (int)fminf(fmaxf(rintf(xv[i].x * sc * wv.x), -128.f), 127.f);
        const int b1 = (int)fminf(fmaxf(rintf(xv[i].y * sc * wv.y), -128.f), 127.f);
        const int b2 = (int)fminf(fmaxf(rintf(xv[i].z * sc * wv.z), -128.f), 127.f);
        const int b3 = (int)fminf(fmaxf(rintf(xv[i].w * sc * wv.w), -128.f), 127.f);
        const int packed = (b0 & 255) | ((b1 & 255) << 8) | ((b2 & 255) << 16) | (b3 << 24);
        const int j4 = tid + i * 256;              // int32 group within row
        const long a32 = ((rb * 64 + (j4 >> 4)) << 11) + (((j4 >> 2) & 3) << 9)
                       + (rr << 2) + (j4 & 3);
        ob[a32] = packed;
    }
}

// ---------------------------------------------------------------------------
// int8 GEMM on tiled-i8 A and W. K-loop: 4 gload_lds + 8 ds_read_b128 +
// 16 MFMA + 1 barrier per wave per step, double-buffered.
// MODE 0: C = acc*s + bias (+residual), fp32 row-major.
// MODE 1: u = acc*s + bias; a = silu(g)*u; out8 = quant(a/qscale), tiled-i8.
template<int MODE>
__global__ __launch_bounds__(256, 4)
void gemm_i8t(const signed char* __restrict__ A8, const signed char* __restrict__ W8,
              const float* __restrict__ scale_ptr, const float* __restrict__ bias,
              const float* __restrict__ residual, float* __restrict__ C,
              const float* __restrict__ gbuf, const float* __restrict__ qscale,
              signed char* __restrict__ out8,
              const int N, const int K, const int gx)
{
    __shared__ __align__(16) signed char lsA[2][8192];
    __shared__ __align__(16) signed char lsB[2][8192];

    int bid = blockIdx.x;
    {   // bijective XCD chunked remap (m204)
        const int nwg = gridDim.x;
        const int q = nwg >> 3, r = nwg & 7;
        const int xcd = bid & 7, idx = bid >> 3;
        bid = (xcd < r) ? (xcd * (q + 1) + idx)
                        : (r * (q + 1) + (xcd - r) * q + idx);
    }
    const int bx = bid % gx, by = bid / gx;

    const int tid  = threadIdx.x;
    const int lane = tid & 63, wid = tid >> 6;
    const int bm = bx << 7, bn = by << 7;
    const int wm = (wid >> 1) << 6, wn = (wid & 1) << 6;

    i32x4 acc[4][4];
#pragma unroll
    for (int m = 0; m < 4; ++m)
#pragma unroll
        for (int n = 0; n < 4; ++n) acc[m][n] = (i32x4){0, 0, 0, 0};

    const int nk = K >> 6;
    const signed char* abase = A8 + ((long)bx * nk << 13);
    const signed char* bbase = W8 + ((long)by * nk << 13);
    const int so0 = wid * 2048 + lane * 16;

    // prologue: stage tile 0
    {
        const signed char* at = abase;
        const signed char* bt = bbase;
        gload_lds16(at + so0,        lsA[0] + wid * 2048);
        gload_lds16(at + so0 + 1024, lsA[0] + wid * 2048 + 1024);
        gload_lds16(bt + so0,        lsB[0] + wid * 2048);
        gload_lds16(bt + so0 + 1024, lsB[0] + wid * 2048 + 1024);
    }
    __syncthreads();

    int cur = 0;
    for (int kt = 0; kt < nk; ++kt) {
        const int nxt = cur ^ 1;
        if (kt + 1 < nk) {
            const signed char* at = abase + ((long)(kt + 1) << 13);
            const signed char* bt = bbase + ((long)(kt + 1) << 13);
            gload_lds16(at + so0,        lsA[nxt] + wid * 2048);
            gload_lds16(at + so0 + 1024, lsA[nxt] + wid * 2048 + 1024);
            gload_lds16(bt + so0,        lsB[nxt] + wid * 2048);
            gload_lds16(bt + so0 + 1024, lsB[nxt] + wid * 2048 + 1024);
        }

        const int kg = (lane >> 4) * 2048, fr = (lane & 15) * 16;
        i32x4 af[4], bf[4];
#pragma unroll
        for (int m = 0; m < 4; ++m)
            af[m] = *(const i32x4*)(lsA[cur] + kg + wm * 16 + m * 256 + fr);
#pragma unroll
        for (int n = 0; n < 4; ++n)
            bf[n] = *(const i32x4*)(lsB[cur] + kg + wn * 16 + n * 256 + fr);
#pragma unroll
        for (int m = 0; m < 4; ++m)
#pragma unroll
            for (int n = 0; n < 4; ++n)
                acc[m][n] = __builtin_amdgcn_mfma_i32_16x16x64_i8(af[m], bf[n], acc[m][n], 0, 0, 0);

        __syncthreads();   // drains next-tile gload_lds + cur-tile ds_reads
        cur = nxt;
    }

    const float s = *scale_ptr;
    const int rq = (lane >> 4) * 4, fc = lane & 15;
    if (MODE == 0) {
#pragma unroll
        for (int m = 0; m < 4; ++m) {
#pragma unroll
            for (int n = 0; n < 4; ++n) {
                const int col = bn + wn + n * 16 + fc;
                const float bcol = bias[col];
#pragma unroll
                for (int r = 0; r < 4; ++r) {
                    const int row = bm + wm + m * 16 + rq + r;
                    float v = (float)acc[m][n][r] * s + bcol;
                    if (residual) v += residual[(long)row * N + col];
                    C[(long)row * N + col] = v;
                }
            }
        }
    } else {
        const float dinv = 1.f / qscale[0];
        const int nko = N >> 6;                    // out tiling over N (=I)
#pragma unroll
        for (int m = 0; m < 4; ++m) {
#pragma unroll
            for (int n = 0; n < 4; ++n) {
                const int col = bn + wn + n * 16 + fc;
                const float bcol = bias[col];
                const int ktc = col >> 6, kgc = (col >> 4) & 3, jc = col & 15;
#pragma unroll
                for (int r = 0; r < 4; ++r) {
                    const int row = bm + wm + m * 16 + rq + r;
                    const float u = (float)acc[m][n][r] * s + bcol;
                    const float g = gbuf[(long)row * N + col];
                    const float a = g / (1.f + __expf(-g)) * u;
                    const float qv = fminf(fmaxf(rintf(a * dinv), -128.f), 127.f);
                    const long addr = (((long)(row >> 7) * nko + ktc) << 13)
                                    + (kgc << 11) + ((row & 127) << 4) + jc;
                    out8[addr] = (signed char)(int)qv;
                }
            }
        }
    }
}

// ---------------------------------------------------------------------------
// RoPE applied in-place to q and k, layout [B,S,NH,HD] == [B,S,H] h-major.
__global__ __launch_bounds__(256)
void rope_k(float* __restrict__ q, float* __restrict__ k)
{
    const int row = blockIdx.x;            // token index b*S+s
    const int s = row & (S_ - 1);
    float* qr = q + (long)row * H_;
    float* kr = k + (long)row * H_;
    for (int t = threadIdx.x; t < NH_ * 64; t += 256) {
        const int nh = t >> 6, i = t & 63;
        const float inv = powf(10000.f, -(float)(2 * i) * (1.f / 128.f));
        const float f = (float)s * inv;
        float sn, c;
        sincosf(f, &sn, &c);
        const int base = nh * 128 + i;
        const float q0 = qr[base], q1 = qr[base + 64];
        qr[base]      = q0 * c - q1 * sn;
        qr[base + 64] = q1 * c + q0 * sn;
        const float k0 = kr[base], k1 = kr[base + 64];
        kr[base]      = k0 * c - k1 * sn;
        kr[base + 64] = k1 * c + k0 * sn;
    }
}

// ---------------------------------------------------------------------------
// Flash attention, bf16 MFMA; epilogue fuses o/o_in_scale quant -> tiled-i8.
__global__ __launch_bounds__(256, 2)
void attn_mfma_k(const float* __restrict__ q, const float* __restrict__ k,
                 const float* __restrict__ v, signed char* __restrict__ out8,
                 const float* __restrict__ osc)
{
    __shared__ __align__(16) char lsK[8192];        // [32 krow][128 d] bf16, XOR swizzle
    __shared__ __align__(16) char lsV[10240];       // V^T [128 d][40 pitch] bf16
    __shared__ __align__(16) char lsP[4][1024];     // per-wave P [16][32] bf16, XOR swizzle

    const int tid = threadIdx.x, lane = tid & 63, wid = tid >> 6;
    const int bid = blockIdx.x;
    const int qt = 15 - (bid >> 6);                 // reversed: long blocks first
    const int bh = bid & 63;
    const int b = bh >> 5, h = bh & 31;
    const int q0 = qt * 64;
    const int qw = q0 + wid * 16;                   // this wave's first q row

    const float* qbase = q + (long)(b * S_) * H_ + (long)h * HD_;
    const float* kbase = k + (long)(b * S_) * H_ + (long)h * HD_;
    const float* vbase = v + (long)(b * S_) * H_ + (long)h * HD_;

    const int frow = lane & 15, fgrp = lane >> 4;
    const float sc = 0.08838834764831845f;          // 1/sqrt(128), folded into Q

    bf16x8 qf[4];
    {
        const float* qr = qbase + (long)(qw + frow) * H_;
#pragma unroll
        for (int c = 0; c < 4; ++c) {
            const float4 a = *(const float4*)(qr + c * 32 + fgrp * 8);
            const float4 bq = *(const float4*)(qr + c * 32 + fgrp * 8 + 4);
            bf16x8 t;
            t[0] = (short)f2bf(a.x * sc);  t[1] = (short)f2bf(a.y * sc);
            t[2] = (short)f2bf(a.z * sc);  t[3] = (short)f2bf(a.w * sc);
            t[4] = (short)f2bf(bq.x * sc); t[5] = (short)f2bf(bq.y * sc);
            t[6] = (short)f2bf(bq.z * sc); t[7] = (short)f2bf(bq.w * sc);
            qf[c] = t;
        }
    }

    f32x4 oacc[8];
#pragma unroll
    for (int n2 = 0; n2 < 8; ++n2) oacc[n2] = (f32x4){0.f, 0.f, 0.f, 0.f};
    float mr[4] = {-1e30f, -1e30f, -1e30f, -1e30f};
    float lr[4] = {0.f, 0.f, 0.f, 0.f};

    const int nt = (q0 >> 5) + 2;
    for (int kt = 0; kt < nt; ++kt) {
        if (kt) __syncthreads();
        {
            const float* kg = kbase + (long)(kt * 32) * H_;
            const float* vg = vbase + (long)(kt * 32) * H_;
#pragma unroll
            for (int i = 0; i < 4; ++i) {
                const int lin = i * 256 + tid;
                const int kr = lin >> 5;
                const int d4 = (lin & 31) * 4;
                const float4 kv = *(const float4*)(kg + (long)kr * H_ + d4);
                const float4 vv = *(const float4*)(vg + (long)kr * H_ + d4);
                ushort4 kb;
                kb.x = f2bf(kv.x); kb.y = f2bf(kv.y); kb.z = f2bf(kv.z); kb.w = f2bf(kv.w);
                *(ushort4*)(lsK + kr * 256 + ((d4 * 2) ^ ((kr & 7) << 4))) = kb;
                *(unsigned short*)(lsV + (d4 + 0) * 80 + kr * 2) = f2bf(vv.x);
                *(unsigned short*)(lsV + (d4 + 1) * 80 + kr * 2) = f2bf(vv.y);
                *(unsigned short*)(lsV + (d4 + 2) * 80 + kr * 2) = f2bf(vv.z);
                *(unsigned short*)(lsV + (d4 + 3) * 80 + kr * 2) = f2bf(vv.w);
            }
        }
        __syncthreads();

        if (kt * 32 <= qw + 15) {
            f32x4 s0 = (f32x4){0.f, 0.f, 0.f, 0.f};
            f32x4 s1 = (f32x4){0.f, 0.f, 0.f, 0.f};
            const int swz = (frow & 7) << 4;
#pragma unroll
            for (int c = 0; c < 4; ++c) {
                const int dby = c * 64 + fgrp * 16;
                const bf16x8 kfA = *(const bf16x8*)(lsK + frow * 256 + (dby ^ swz));
                const bf16x8 kfB = *(const bf16x8*)(lsK + (frow + 16) * 256 + (dby ^ swz));
                s0 = __builtin_amdgcn_mfma_f32_16x16x32_bf16(qf[c], kfA, s0, 0, 0, 0);
                s1 = __builtin_amdgcn_mfma_f32_16x16x32_bf16(qf[c], kfB, s1, 0, 0, 0);
            }

            const int colg0 = kt * 32 + frow;
            float cf[4];
#pragma unroll
            for (int r = 0; r < 4; ++r) {
                const int rowg = qw + fgrp * 4 + r;
                const float a0 = (colg0 <= rowg) ? s0[r] : -1e30f;
                const float a1 = (colg0 + 16 <= rowg) ? s1[r] : -1e30f;
                float mx = fmaxf(a0, a1);
#pragma unroll
                for (int off2 = 1; off2 < 16; off2 <<= 1) mx = fmaxf(mx, __shfl_xor(mx, off2));
                const float mnew = fmaxf(mr[r], mx);
                cf[r] = __expf(mr[r] - mnew);
                mr[r] = mnew;
                const float p0 = __expf(a0 - mnew);
                const float p1 = __expf(a1 - mnew);
                float sm = p0 + p1;
#pragma unroll
                for (int off2 = 1; off2 < 16; off2 <<= 1) sm += __shfl_xor(sm, off2);
                lr[r] = lr[r] * cf[r] + sm;
                const int row = fgrp * 4 + r;
                const int psw = (row & 3) << 4;
                *(unsigned short*)(lsP[wid] + row * 64 + ((frow * 2) ^ psw)) = f2bf(p0);
                *(unsigned short*)(lsP[wid] + row * 64 + (((16 + frow) * 2) ^ psw)) = f2bf(p1);
            }
#pragma unroll
            for (int n2 = 0; n2 < 8; ++n2) {
#pragma unroll
                for (int r = 0; r < 4; ++r) oacc[n2][r] *= cf[r];
            }
            const bf16x8 pf = *(const bf16x8*)(lsP[wid] + frow * 64 + ((fgrp * 16) ^ ((frow & 3) << 4)));
#pragma unroll
            for (int n2 = 0; n2 < 8; ++n2) {
                const bf16x8 vf = *(const bf16x8*)(lsV + (n2 * 16 + frow) * 80 + fgrp * 16);
                oacc[n2] = __builtin_amdgcn_mfma_f32_16x16x32_bf16(pf, vf, oacc[n2], 0, 0, 0);
            }
        }
    }

    // epilogue: o = oacc/l, q8 = clip(rint(o/osc)) -> tiled-i8 (nk = 64)
    const float oinv = 1.f / osc[0];
    float inv[4];
#pragma unroll
    for (int r = 0; r < 4; ++r) inv[r] = 1.f / lr[r];
#pragma unroll
    for (int n2 = 0; n2 < 8; ++n2) {
        const int kk = h * 128 + n2 * 16 + frow;
        const int ktc = kk >> 6, kgc = (kk >> 4) & 3, jc = kk & 15;
#pragma unroll
        for (int r = 0; r < 4; ++r) {
            const int rowt = b * S_ + qw + fgrp * 4 + r;
            const float ov = oacc[n2][r] * inv[r];
            const float qv = fminf(fmaxf(rintf(ov * oinv), -128.f), 127.f);
            const long addr = (((long)(rowt >> 7) * 64 + ktc) << 13)
                            + (kgc << 11) + ((rowt & 127) << 4) + jc;
            out8[addr] = (signed char)(int)qv;
        }
    }
}

// ---------------------------------------------------------------------------
extern "C" void kernel_launch(void* const* d_in, const int* in_sizes, int n_in,
                              void* d_out, int out_size, void* d_ws, size_t ws_size,
                              hipStream_t stream)
{
    const float* hidden = (const float*)d_in[0];
    const float* ln1 = (const float*)d_in[1];
    const float* ln2 = (const float*)d_in[2];
    const int* Wq = (const int*)d_in[3];
    const int* Wk = (const int*)d_in[4];
    const int* Wv = (const int*)d_in[5];
    const int* Wo = (const int*)d_in[6];
    const int* Wg = (const int*)d_in[7];
    const int* Wu = (const int*)d_in[8];
    const int* Wd = (const int*)d_in[9];
    const float* bq = (const float*)d_in[10];
    const float* bk = (const float*)d_in[11];
    const float* bv = (const float*)d_in[12];
    const float* bo = (const float*)d_in[13];
    const float* bg = (const float*)d_in[14];
    const float* bu = (const float*)d_in[15];
    const float* bd = (const float*)d_in[16];
    const float* sq = (const float*)d_in[17];
    const float* sk = (const float*)d_in[18];
    const float* sv = (const float*)d_in[19];
    const float* so = (const float*)d_in[20];
    const float* sg = (const float*)d_in[21];
    const float* su = (const float*)d_in[22];
    const float* sd = (const float*)d_in[23];
    const float* o_sc = (const float*)d_in[24];
    const float* d_sc = (const float*)d_in[25];

    // workspace (MiB offsets, peak 206 MiB):
    //  [0,22)    A8 tiled int8: hq / oq / hq2 (8 MiB each, sequential reuse)
    //  [22,66)   WP: packed-W scratch (max 43.01 MiB)
    //  [66,98)   Qb fp32 -> (post-attn) Hb
    //  [98,130)  Kb ; [130,162) Vb ; [98,184) Gb (after attn, K/V dead)
    //  [184,206) AQ8 tiled int8 (2048 x 11008)
    char* ws = (char*)d_ws;
    signed char* HQ8 = (signed char*)ws;
    signed char* WP  = (signed char*)(ws + ((size_t)22 << 20));
    float* Qb = (float*)(ws + ((size_t)66 << 20));
    float* Kb = (float*)(ws + ((size_t)98 << 20));
    float* Vb = (float*)(ws + ((size_t)130 << 20));
    float* Gb = (float*)(ws + ((size_t)98 << 20));
    signed char* AQ8 = (signed char*)(ws + ((size_t)184 << 20));
    float* Hb = Qb;
    float* out = (float*)d_out;

    const dim3 blk(256);
    const int gxH = R_ / 128;                 // 16 row blocks
    const int nwgH = gxH * (H_ / 128);        // 512
    const int nwgI = gxH * (I_ / 128);        // 1376
    const dim3 gpH(H_ / 64, H_ / 128);        // pack grids: (nk, N/128)
    const dim3 gpI(H_ / 64, I_ / 128);
    const dim3 gpD(I_ / 64, H_ / 128);

    rmsnorm_quant_k<<<R_, blk, 0, stream>>>(hidden, ln1, HQ8);

    packW_k<<<gpH, blk, 0, stream>>>(Wq, WP, H_);
    gemm_i8t<0><<<nwgH, blk, 0, stream>>>(HQ8, WP, sq, bq, nullptr, Qb,
                                          nullptr, nullptr, nullptr, H_, H_, gxH);
    packW_k<<<gpH, blk, 0, stream>>>(Wk, WP, H_);
    gemm_i8t<0><<<nwgH, blk, 0, stream>>>(HQ8, WP, sk, bk, nullptr, Kb,
                                          nullptr, nullptr, nullptr, H_, H_, gxH);
    packW_k<<<gpH, blk, 0, stream>>>(Wv, WP, H_);
    gemm_i8t<0><<<nwgH, blk, 0, stream>>>(HQ8, WP, sv, bv, nullptr, Vb,
                                          nullptr, nullptr, nullptr, H_, H_, gxH);

    rope_k<<<R_, blk, 0, stream>>>(Qb, Kb);
    attn_mfma_k<<<B_ * NH_ * (S_ / 64), blk, 0, stream>>>(Qb, Kb, Vb, HQ8, o_sc);

    packW_k<<<gpH, blk, 0, stream>>>(Wo, WP, H_);
    gemm_i8t<0><<<nwgH, blk, 0, stream>>>(HQ8, WP, so, bo, hidden, Hb,
                                          nullptr, nullptr, nullptr, H_, H_, gxH);

    rmsnorm_quant_k<<<R_, blk, 0, stream>>>(Hb, ln2, HQ8);

    packW_k<<<gpI, blk, 0, stream>>>(Wg, WP, H_);
    gemm_i8t<0><<<nwgI, blk, 0, stream>>>(HQ8, WP, sg, bg, nullptr, Gb,
                                          nullptr, nullptr, nullptr, I_, H_, gxH);
    packW_k<<<gpI, blk, 0, stream>>>(Wu, WP, H_);
    gemm_i8t<1><<<nwgI, blk, 0, stream>>>(HQ8, WP, su, bu, nullptr, nullptr,
                                          Gb, d_sc, AQ8, I_, H_, gxH);
    packW_k<<<gpD, blk, 0, stream>>>(Wd, WP, I_);
    gemm_i8t<0><<<nwgH, blk, 0, stream>>>(AQ8, WP, sd, bd, Hb, out,
                                          nullptr, nullptr, nullptr, H_, I_, gxH);
}

// Round 5
// 997.101 us; speedup vs baseline: 2.6069x; 1.0068x over previous
//
#include <hip/hip_runtime.h>
#include <math.h>

#define B_  2
#define S_  1024
#define H_  4096
#define NH_ 32
#define HD_ 128
#define I_  11008
#define R_  2048   // B*S tokens

typedef __attribute__((ext_vector_type(4))) int i32x4;
typedef __attribute__((ext_vector_type(4))) float f32x4;
typedef __attribute__((ext_vector_type(8))) short bf16x8;

// Tiled int8 activation/weight layout ("tile image"): for matrix [Rows][K],
// nk = K/64; tile (rb, kt) is 8192 B at ((rb*nk + kt)<<13), internally
// [kgrp 0..3][row 0..127][16B]  (kgrp = (k%64)/16). This is exactly the LDS
// image the MFMA fragment reads expect -> staging is contiguous 1KB chunks.

// ---------------------------------------------------------------------------
__device__ __forceinline__ void gload_lds16(const void* g, void* l) {
    __builtin_amdgcn_global_load_lds(
        (const __attribute__((address_space(1))) unsigned int*)g,
        (__attribute__((address_space(3))) unsigned int*)l, 16, 0, 0);
}

__device__ __forceinline__ unsigned short f2bf(float f) {
    unsigned int u = __float_as_uint(f);
    u += 0x7fffu + ((u >> 16) & 1u);   // RNE
    return (unsigned short)(u >> 16);
}

// ---------------------------------------------------------------------------
// Pack one W (int32 [N][K]) into tiled-i8. Grid: (nk, N/128).
__global__ __launch_bounds__(256)
void packW_k(const int* __restrict__ W, signed char* __restrict__ out, const int K)
{
    const int kt = blockIdx.x, cb = blockIdx.y, nk = gridDim.x;
    const int t = threadIdx.x;
    int* otile = (int*)(out + ((long)(cb * nk + kt) << 13));
#pragma unroll
    for (int i = 0; i < 8; ++i) {
        const int o = i * 256 + t;                 // int32 index in tile
        const int g = o >> 9, r = (o >> 2) & 127, jj = o & 3;
        const int4 w4 = *(const int4*)(W + (long)(cb * 128 + r) * K + kt * 64 + g * 16 + jj * 4);
        otile[o] = (w4.x & 255) | ((w4.y & 255) << 8) | ((w4.z & 255) << 16) | (w4.w << 24);
    }
}

// ---------------------------------------------------------------------------
// RMSNorm + int8 quant (scale folded into w). Output in tiled-i8 (nk=64).
__global__ __launch_bounds__(256)
void rmsnorm_quant_k(const float* __restrict__ x, const float* __restrict__ w,
                     signed char* __restrict__ out)
{
    __shared__ float red[4];
    const int tid = threadIdx.x;
    const long row = blockIdx.x;
    const float4* xr = (const float4*)(x + row * H_);
    float4 xv[4];
    float ss = 0.f;
#pragma unroll
    for (int i = 0; i < 4; ++i) {
        xv[i] = xr[tid + i * 256];
        ss += xv[i].x * xv[i].x + xv[i].y * xv[i].y
            + xv[i].z * xv[i].z + xv[i].w * xv[i].w;
    }
#pragma unroll
    for (int off = 32; off; off >>= 1) ss += __shfl_xor(ss, off);
    if ((tid & 63) == 0) red[tid >> 6] = ss;
    __syncthreads();
    const float tot = red[0] + red[1] + red[2] + red[3];
    const float sc = 1.f / sqrtf(tot * (1.f / (float)H_) + 1e-6f);
    const float4* wr = (const float4*)w;
    int* ob = (int*)out;
    const long rb = row >> 7;
    const int rr = (int)(row & 127);
#pragma unroll
    for (int i = 0; i < 4; ++i) {
        const float4 wv = wr[tid + i * 256];
        const int b0 = (int)fminf(fmaxf(rintf(xv[i].x * sc * wv.x), -128.f), 127.f);
        const int b1 = (int)fminf(fmaxf(rintf(xv[i].y * sc * wv.y), -128.f), 127.f);
        const int b2 = (int)fminf(fmaxf(rintf(xv[i].z * sc * wv.z), -128.f), 127.f);
        const int b3 = (int)fminf(fmaxf(rintf(xv[i].w * sc * wv.w), -128.f), 127.f);
        const int packed = (b0 & 255) | ((b1 & 255) << 8) | ((b2 & 255) << 16) | (b3 << 24);
        const int j4 = tid + i * 256;              // int32 group within row
        const long a32 = ((rb * 64 + (j4 >> 4)) << 11) + (((j4 >> 2) & 3) << 9)
                       + (rr << 2) + (j4 & 3);
        ob[a32] = packed;
    }
}

// ---------------------------------------------------------------------------
// int8 GEMM on tiled-i8 A and W. Depth-3 pipelined K-loop: issue tile kt+2,
// counted s_waitcnt vmcnt(8/4/0) (never 0 mid-loop), raw s_barrier pair,
// setprio around the 16-MFMA cluster. 48KB LDS -> 3 blocks/CU.
// MODE 0: C = acc*s + bias (+residual), fp32 row-major.
// MODE 1: u = acc*s + bias; a = silu(g)*u; out8 = quant(a/qscale), tiled-i8.
template<int MODE>
__global__ __launch_bounds__(256, 3)
void gemm_i8t(const signed char* __restrict__ A8, const signed char* __restrict__ W8,
              const float* __restrict__ scale_ptr, const float* __restrict__ bias,
              const float* __restrict__ residual, float* __restrict__ C,
              const float* __restrict__ gbuf, const float* __restrict__ qscale,
              signed char* __restrict__ out8,
              const int N, const int K, const int gx)
{
    __shared__ __align__(16) signed char lsA[3][8192];
    __shared__ __align__(16) signed char lsB[3][8192];

    int bid = blockIdx.x;
    {   // bijective XCD chunked remap (m204)
        const int nwg = gridDim.x;
        const int q = nwg >> 3, r = nwg & 7;
        const int xcd = bid & 7, idx = bid >> 3;
        bid = (xcd < r) ? (xcd * (q + 1) + idx)
                        : (r * (q + 1) + (xcd - r) * q + idx);
    }
    const int bx = bid % gx, by = bid / gx;

    const int tid  = threadIdx.x;
    const int lane = tid & 63, wid = tid >> 6;
    const int bm = bx << 7, bn = by << 7;
    const int wm = (wid >> 1) << 6, wn = (wid & 1) << 6;

    i32x4 acc[4][4];
#pragma unroll
    for (int m = 0; m < 4; ++m)
#pragma unroll
        for (int n = 0; n < 4; ++n) acc[m][n] = (i32x4){0, 0, 0, 0};

    const int nk = K >> 6;
    const signed char* abase = A8 + ((long)bx * nk << 13);
    const signed char* bbase = W8 + ((long)by * nk << 13);
    const int so0 = wid * 2048 + lane * 16;
    const int ld0 = wid * 2048;

    // prologue: issue tiles 0 and 1 (8 gloads outstanding)
#pragma unroll
    for (int t = 0; t < 2; ++t) {
        const signed char* at = abase + ((long)t << 13);
        const signed char* bt = bbase + ((long)t << 13);
        gload_lds16(at + so0,        lsA[t] + ld0);
        gload_lds16(at + so0 + 1024, lsA[t] + ld0 + 1024);
        gload_lds16(bt + so0,        lsB[t] + ld0);
        gload_lds16(bt + so0 + 1024, lsB[t] + ld0 + 1024);
    }

    for (int kt = 0; kt < nk; ++kt) {
        const int cur = kt % 3;
        if (kt + 2 < nk) {                         // issue tile kt+2 (buffer freed
            const int pb = (kt + 2) % 3;           //  at prev iter's barrier B)
            const signed char* at = abase + ((long)(kt + 2) << 13);
            const signed char* bt = bbase + ((long)(kt + 2) << 13);
            gload_lds16(at + so0,        lsA[pb] + ld0);
            gload_lds16(at + so0 + 1024, lsA[pb] + ld0 + 1024);
            gload_lds16(bt + so0,        lsB[pb] + ld0);
            gload_lds16(bt + so0 + 1024, lsB[pb] + ld0 + 1024);
        }
        // wait ONLY tile kt's 4 loads; younger tiles stay in flight (T4)
        if (kt + 2 < nk)      asm volatile("s_waitcnt vmcnt(8)" ::: "memory");
        else if (kt + 1 < nk) asm volatile("s_waitcnt vmcnt(4)" ::: "memory");
        else                  asm volatile("s_waitcnt vmcnt(0)" ::: "memory");
        __builtin_amdgcn_s_barrier();              // barrier A: tile kt visible

        const int kg = (lane >> 4) * 2048, fr = (lane & 15) * 16;
        i32x4 af[4], bf[4];
#pragma unroll
        for (int m = 0; m < 4; ++m)
            af[m] = *(const i32x4*)(lsA[cur] + kg + wm * 16 + m * 256 + fr);
#pragma unroll
        for (int n = 0; n < 4; ++n)
            bf[n] = *(const i32x4*)(lsB[cur] + kg + wn * 16 + n * 256 + fr);
        __builtin_amdgcn_s_setprio(1);
#pragma unroll
        for (int m = 0; m < 4; ++m)
#pragma unroll
            for (int n = 0; n < 4; ++n)
                acc[m][n] = __builtin_amdgcn_mfma_i32_16x16x64_i8(af[m], bf[n], acc[m][n], 0, 0, 0);
        __builtin_amdgcn_s_setprio(0);
        __builtin_amdgcn_s_barrier();              // barrier B: buf[cur] free
    }

    const float s = *scale_ptr;
    const int rq = (lane >> 4) * 4, fc = lane & 15;
    if (MODE == 0) {
#pragma unroll
        for (int m = 0; m < 4; ++m) {
#pragma unroll
            for (int n = 0; n < 4; ++n) {
                const int col = bn + wn + n * 16 + fc;
                const float bcol = bias[col];
#pragma unroll
                for (int r = 0; r < 4; ++r) {
                    const int row = bm + wm + m * 16 + rq + r;
                    float v = (float)acc[m][n][r] * s + bcol;
                    if (residual) v += residual[(long)row * N + col];
                    C[(long)row * N + col] = v;
                }
            }
        }
    } else {
        const float dinv = 1.f / qscale[0];
        const int nko = N >> 6;                    // out tiling over N (=I)
#pragma unroll
        for (int m = 0; m < 4; ++m) {
#pragma unroll
            for (int n = 0; n < 4; ++n) {
                const int col = bn + wn + n * 16 + fc;
                const float bcol = bias[col];
                const int ktc = col >> 6, kgc = (col >> 4) & 3, jc = col & 15;
#pragma unroll
                for (int r = 0; r < 4; ++r) {
                    const int row = bm + wm + m * 16 + rq + r;
                    const float u = (float)acc[m][n][r] * s + bcol;
                    const float g = gbuf[(long)row * N + col];
                    const float a = g / (1.f + __expf(-g)) * u;
                    const float qv = fminf(fmaxf(rintf(a * dinv), -128.f), 127.f);
                    const long addr = (((long)(row >> 7) * nko + ktc) << 13)
                                    + (kgc << 11) + ((row & 127) << 4) + jc;
                    out8[addr] = (signed char)(int)qv;
                }
            }
        }
    }
}

// ---------------------------------------------------------------------------
// RoPE applied in-place to q and k, layout [B,S,NH,HD] == [B,S,H] h-major.
__global__ __launch_bounds__(256)
void rope_k(float* __restrict__ q, float* __restrict__ k)
{
    const int row = blockIdx.x;            // token index b*S+s
    const int s = row & (S_ - 1);
    float* qr = q + (long)row * H_;
    float* kr = k + (long)row * H_;
    for (int t = threadIdx.x; t < NH_ * 64; t += 256) {
        const int nh = t >> 6, i = t & 63;
        const float inv = powf(10000.f, -(float)(2 * i) * (1.f / 128.f));
        const float f = (float)s * inv;
        float sn, c;
        sincosf(f, &sn, &c);
        const int base = nh * 128 + i;
        const float q0 = qr[base], q1 = qr[base + 64];
        qr[base]      = q0 * c - q1 * sn;
        qr[base + 64] = q1 * c + q0 * sn;
        const float k0 = kr[base], k1 = kr[base + 64];
        kr[base]      = k0 * c - k1 * sn;
        kr[base + 64] = k1 * c + k0 * sn;
    }
}

// ---------------------------------------------------------------------------
// Flash attention, bf16 MFMA; epilogue fuses o/o_in_scale quant -> tiled-i8.
__global__ __launch_bounds__(256, 2)
void attn_mfma_k(const float* __restrict__ q, const float* __restrict__ k,
                 const float* __restrict__ v, signed char* __restrict__ out8,
                 const float* __restrict__ osc)
{
    __shared__ __align__(16) char lsK[8192];        // [32 krow][128 d] bf16, XOR swizzle
    __shared__ __align__(16) char lsV[10240];       // V^T [128 d][40 pitch] bf16
    __shared__ __align__(16) char lsP[4][1024];     // per-wave P [16][32] bf16, XOR swizzle

    const int tid = threadIdx.x, lane = tid & 63, wid = tid >> 6;
    const int bid = blockIdx.x;
    const int qt = 15 - (bid >> 6);                 // reversed: long blocks first
    const int bh = bid & 63;
    const int b = bh >> 5, h = bh & 31;
    const int q0 = qt * 64;
    const int qw = q0 + wid * 16;                   // this wave's first q row

    const float* qbase = q + (long)(b * S_) * H_ + (long)h * HD_;
    const float* kbase = k + (long)(b * S_) * H_ + (long)h * HD_;
    const float* vbase = v + (long)(b * S_) * H_ + (long)h * HD_;

    const int frow = lane & 15, fgrp = lane >> 4;
    const float sc = 0.08838834764831845f;          // 1/sqrt(128), folded into Q

    bf16x8 qf[4];
    {
        const float* qr = qbase + (long)(qw + frow) * H_;
#pragma unroll
        for (int c = 0; c < 4; ++c) {
            const float4 a = *(const float4*)(qr + c * 32 + fgrp * 8);
            const float4 bq = *(const float4*)(qr + c * 32 + fgrp * 8 + 4);
            bf16x8 t;
            t[0] = (short)f2bf(a.x * sc);  t[1] = (short)f2bf(a.y * sc);
            t[2] = (short)f2bf(a.z * sc);  t[3] = (short)f2bf(a.w * sc);
            t[4] = (short)f2bf(bq.x * sc); t[5] = (short)f2bf(bq.y * sc);
            t[6] = (short)f2bf(bq.z * sc); t[7] = (short)f2bf(bq.w * sc);
            qf[c] = t;
        }
    }

    f32x4 oacc[8];
#pragma unroll
    for (int n2 = 0; n2 < 8; ++n2) oacc[n2] = (f32x4){0.f, 0.f, 0.f, 0.f};
    float mr[4] = {-1e30f, -1e30f, -1e30f, -1e30f};
    float lr[4] = {0.f, 0.f, 0.f, 0.f};

    const int nt = (q0 >> 5) + 2;
    for (int kt = 0; kt < nt; ++kt) {
        if (kt) __syncthreads();
        {
            const float* kg = kbase + (long)(kt * 32) * H_;
            const float* vg = vbase + (long)(kt * 32) * H_;
#pragma unroll
            for (int i = 0; i < 4; ++i) {
                const int lin = i * 256 + tid;
                const int kr = lin >> 5;
                const int d4 = (lin & 31) * 4;
                const float4 kv = *(const float4*)(kg + (long)kr * H_ + d4);
                const float4 vv = *(const float4*)(vg + (long)kr * H_ + d4);
                ushort4 kb;
                kb.x = f2bf(kv.x); kb.y = f2bf(kv.y); kb.z = f2bf(kv.z); kb.w = f2bf(kv.w);
                *(ushort4*)(lsK + kr * 256 + ((d4 * 2) ^ ((kr & 7) << 4))) = kb;
                *(unsigned short*)(lsV + (d4 + 0) * 80 + kr * 2) = f2bf(vv.x);
                *(unsigned short*)(lsV + (d4 + 1) * 80 + kr * 2) = f2bf(vv.y);
                *(unsigned short*)(lsV + (d4 + 2) * 80 + kr * 2) = f2bf(vv.z);
                *(unsigned short*)(lsV + (d4 + 3) * 80 + kr * 2) = f2bf(vv.w);
            }
        }
        __syncthreads();

        if (kt * 32 <= qw + 15) {
            f32x4 s0 = (f32x4){0.f, 0.f, 0.f, 0.f};
            f32x4 s1 = (f32x4){0.f, 0.f, 0.f, 0.f};
            const int swz = (frow & 7) << 4;
#pragma unroll
            for (int c = 0; c < 4; ++c) {
                const int dby = c * 64 + fgrp * 16;
                const bf16x8 kfA = *(const bf16x8*)(lsK + frow * 256 + (dby ^ swz));
                const bf16x8 kfB = *(const bf16x8*)(lsK + (frow + 16) * 256 + (dby ^ swz));
                s0 = __builtin_amdgcn_mfma_f32_16x16x32_bf16(qf[c], kfA, s0, 0, 0, 0);
                s1 = __builtin_amdgcn_mfma_f32_16x16x32_bf16(qf[c], kfB, s1, 0, 0, 0);
            }

            const int colg0 = kt * 32 + frow;
            float cf[4];
#pragma unroll
            for (int r = 0; r < 4; ++r) {
                const int rowg = qw + fgrp * 4 + r;
                const float a0 = (colg0 <= rowg) ? s0[r] : -1e30f;
                const float a1 = (colg0 + 16 <= rowg) ? s1[r] : -1e30f;
                float mx = fmaxf(a0, a1);
#pragma unroll
                for (int off2 = 1; off2 < 16; off2 <<= 1) mx = fmaxf(mx, __shfl_xor(mx, off2));
                const float mnew = fmaxf(mr[r], mx);
                cf[r] = __expf(mr[r] - mnew);
                mr[r] = mnew;
                const float p0 = __expf(a0 - mnew);
                const float p1 = __expf(a1 - mnew);
                float sm = p0 + p1;
#pragma unroll
                for (int off2 = 1; off2 < 16; off2 <<= 1) sm += __shfl_xor(sm, off2);
                lr[r] = lr[r] * cf[r] + sm;
                const int row = fgrp * 4 + r;
                const int psw = (row & 3) << 4;
                *(unsigned short*)(lsP[wid] + row * 64 + ((frow * 2) ^ psw)) = f2bf(p0);
                *(unsigned short*)(lsP[wid] + row * 64 + (((16 + frow) * 2) ^ psw)) = f2bf(p1);
            }
#pragma unroll
            for (int n2 = 0; n2 < 8; ++n2) {
#pragma unroll
                for (int r = 0; r < 4; ++r) oacc[n2][r] *= cf[r];
            }
            const bf16x8 pf = *(const bf16x8*)(lsP[wid] + frow * 64 + ((fgrp * 16) ^ ((frow & 3) << 4)));
#pragma unroll
            for (int n2 = 0; n2 < 8; ++n2) {
                const bf16x8 vf = *(const bf16x8*)(lsV + (n2 * 16 + frow) * 80 + fgrp * 16);
                oacc[n2] = __builtin_amdgcn_mfma_f32_16x16x32_bf16(pf, vf, oacc[n2], 0, 0, 0);
            }
        }
    }

    // epilogue: o = oacc/l, q8 = clip(rint(o/osc)) -> tiled-i8 (nk = 64)
    const float oinv = 1.f / osc[0];
    float inv[4];
#pragma unroll
    for (int r = 0; r < 4; ++r) inv[r] = 1.f / lr[r];
#pragma unroll
    for (int n2 = 0; n2 < 8; ++n2) {
        const int kk = h * 128 + n2 * 16 + frow;
        const int ktc = kk >> 6, kgc = (kk >> 4) & 3, jc = kk & 15;
#pragma unroll
        for (int r = 0; r < 4; ++r) {
            const int rowt = b * S_ + qw + fgrp * 4 + r;
            const float ov = oacc[n2][r] * inv[r];
            const float qv = fminf(fmaxf(rintf(ov * oinv), -128.f), 127.f);
            const long addr = (((long)(rowt >> 7) * 64 + ktc) << 13)
                            + (kgc << 11) + ((rowt & 127) << 4) + jc;
            out8[addr] = (signed char)(int)qv;
        }
    }
}

// ---------------------------------------------------------------------------
extern "C" void kernel_launch(void* const* d_in, const int* in_sizes, int n_in,
                              void* d_out, int out_size, void* d_ws, size_t ws_size,
                              hipStream_t stream)
{
    const float* hidden = (const float*)d_in[0];
    const float* ln1 = (const float*)d_in[1];
    const float* ln2 = (const float*)d_in[2];
    const int* Wq = (const int*)d_in[3];
    const int* Wk = (const int*)d_in[4];
    const int* Wv = (const int*)d_in[5];
    const int* Wo = (const int*)d_in[6];
    const int* Wg = (const int*)d_in[7];
    const int* Wu = (const int*)d_in[8];
    const int* Wd = (const int*)d_in[9];
    const float* bq = (const float*)d_in[10];
    const float* bk = (const float*)d_in[11];
    const float* bv = (const float*)d_in[12];
    const float* bo = (const float*)d_in[13];
    const float* bg = (const float*)d_in[14];
    const float* bu = (const float*)d_in[15];
    const float* bd = (const float*)d_in[16];
    const float* sq = (const float*)d_in[17];
    const float* sk = (const float*)d_in[18];
    const float* sv = (const float*)d_in[19];
    const float* so = (const float*)d_in[20];
    const float* sg = (const float*)d_in[21];
    const float* su = (const float*)d_in[22];
    const float* sd = (const float*)d_in[23];
    const float* o_sc = (const float*)d_in[24];
    const float* d_sc = (const float*)d_in[25];

    // workspace (MiB offsets, peak 206 MiB):
    //  [0,22)    A8 tiled int8: hq / oq / hq2 (8 MiB each, sequential reuse)
    //  [22,66)   WP: packed-W scratch (max 43.01 MiB)
    //  [66,98)   Qb fp32 -> (post-attn) Hb
    //  [98,130)  Kb ; [130,162) Vb ; [98,184) Gb (after attn, K/V dead)
    //  [184,206) AQ8 tiled int8 (2048 x 11008)
    char* ws = (char*)d_ws;
    signed char* HQ8 = (signed char*)ws;
    signed char* WP  = (signed char*)(ws + ((size_t)22 << 20));
    float* Qb = (float*)(ws + ((size_t)66 << 20));
    float* Kb = (float*)(ws + ((size_t)98 << 20));
    float* Vb = (float*)(ws + ((size_t)130 << 20));
    float* Gb = (float*)(ws + ((size_t)98 << 20));
    signed char* AQ8 = (signed char*)(ws + ((size_t)184 << 20));
    float* Hb = Qb;
    float* out = (float*)d_out;

    const dim3 blk(256);
    const int gxH = R_ / 128;                 // 16 row blocks
    const int nwgH = gxH * (H_ / 128);        // 512
    const int nwgI = gxH * (I_ / 128);        // 1376
    const dim3 gpH(H_ / 64, H_ / 128);        // pack grids: (nk, N/128)
    const dim3 gpI(H_ / 64, I_ / 128);
    const dim3 gpD(I_ / 64, H_ / 128);

    rmsnorm_quant_k<<<R_, blk, 0, stream>>>(hidden, ln1, HQ8);

    packW_k<<<gpH, blk, 0, stream>>>(Wq, WP, H_);
    gemm_i8t<0><<<nwgH, blk, 0, stream>>>(HQ8, WP, sq, bq, nullptr, Qb,
                                          nullptr, nullptr, nullptr, H_, H_, gxH);
    packW_k<<<gpH, blk, 0, stream>>>(Wk, WP, H_);
    gemm_i8t<0><<<nwgH, blk, 0, stream>>>(HQ8, WP, sk, bk, nullptr, Kb,
                                          nullptr, nullptr, nullptr, H_, H_, gxH);
    packW_k<<<gpH, blk, 0, stream>>>(Wv, WP, H_);
    gemm_i8t<0><<<nwgH, blk, 0, stream>>>(HQ8, WP, sv, bv, nullptr, Vb,
                                          nullptr, nullptr, nullptr, H_, H_, gxH);

    rope_k<<<R_, blk, 0, stream>>>(Qb, Kb);
    attn_mfma_k<<<B_ * NH_ * (S_ / 64), blk, 0, stream>>>(Qb, Kb, Vb, HQ8, o_sc);

    packW_k<<<gpH, blk, 0, stream>>>(Wo, WP, H_);
    gemm_i8t<0><<<nwgH, blk, 0, stream>>>(HQ8, WP, so, bo, hidden, Hb,
                                          nullptr, nullptr, nullptr, H_, H_, gxH);

    rmsnorm_quant_k<<<R_, blk, 0, stream>>>(Hb, ln2, HQ8);

    packW_k<<<gpI, blk, 0, stream>>>(Wg, WP, H_);
    gemm_i8t<0><<<nwgI, blk, 0, stream>>>(HQ8, WP, sg, bg, nullptr, Gb,
                                          nullptr, nullptr, nullptr, I_, H_, gxH);
    packW_k<<<gpI, blk, 0, stream>>>(Wu, WP, H_);
    gemm_i8t<1><<<nwgI, blk, 0, stream>>>(HQ8, WP, su, bu, nullptr, nullptr,
                                          Gb, d_sc, AQ8, I_, H_, gxH);
    packW_k<<<gpD, blk, 0, stream>>>(Wd, WP, I_);
    gemm_i8t<0><<<nwgH, blk, 0, stream>>>(AQ8, WP, sd, bd, Hb, out,
                                          nullptr, nullptr, nullptr, H_, I_, gxH);
}

// Round 8
// 941.442 us; speedup vs baseline: 2.7610x; 1.0591x over previous
//
#include <hip/hip_runtime.h>
#include <math.h>

#define B_  2
#define S_  1024
#define H_  4096
#define NH_ 32
#define HD_ 128
#define I_  11008
#define R_  2048   // B*S tokens

typedef __attribute__((ext_vector_type(4))) int i32x4;
typedef __attribute__((ext_vector_type(4))) float f32x4;
typedef __attribute__((ext_vector_type(8))) short bf16x8;

// Tiled int8 layout (v1, round-5 validated): for matrix [Rows][K], nk = K/64;
// tile (rb, kt) is 8192 B at ((rb*nk + kt)<<13), internally
// [kgrp 0..3][row 0..127][16B]  (kgrp = (k%64)/16). Two consecutive tiles
// (2t, 2t+1) are 16KB contiguous -> one BK=128 staging unit.

// ---------------------------------------------------------------------------
// global->LDS DMA. NOTE (r7 lesson): the GLOBAL src address is PER-LANE
// (must include lane*16); the LDS dest is wave-uniform, HW adds lane*16.
__device__ __forceinline__ void gload_lds16(const void* g, void* l) {
    __builtin_amdgcn_global_load_lds(
        (const __attribute__((address_space(1))) unsigned int*)g,
        (__attribute__((address_space(3))) unsigned int*)l, 16, 0, 0);
}

__device__ __forceinline__ unsigned short f2bf(float f) {
    unsigned int u = __float_as_uint(f);
    u += 0x7fffu + ((u >> 16) & 1u);   // RNE
    return (unsigned short)(u >> 16);
}

// ---------------------------------------------------------------------------
// Pack one W (int32 [N][K]) into tiled-i8. Grid: (K/64, N/128).
__global__ __launch_bounds__(256)
void packW_k(const int* __restrict__ W, signed char* __restrict__ out, const int K)
{
    const int kt = blockIdx.x, cb = blockIdx.y, nk = gridDim.x;
    const int t = threadIdx.x;
    int* otile = (int*)(out + ((long)(cb * nk + kt) << 13));
#pragma unroll
    for (int i = 0; i < 8; ++i) {
        const int o = i * 256 + t;                 // int32 index in tile
        const int g = o >> 9, r = (o >> 2) & 127, jj = o & 3;
        const int4 w4 = *(const int4*)(W + (long)(cb * 128 + r) * K + kt * 64 + g * 16 + jj * 4);
        otile[o] = (w4.x & 255) | ((w4.y & 255) << 8) | ((w4.z & 255) << 16) | (w4.w << 24);
    }
}

// ---------------------------------------------------------------------------
// RMSNorm + int8 quant (scale folded into w). Output in tiled-i8 (nk=64).
__global__ __launch_bounds__(256)
void rmsnorm_quant_k(const float* __restrict__ x, const float* __restrict__ w,
                     signed char* __restrict__ out)
{
    __shared__ float red[4];
    const int tid = threadIdx.x;
    const long row = blockIdx.x;
    const float4* xr = (const float4*)(x + row * H_);
    float4 xv[4];
    float ss = 0.f;
#pragma unroll
    for (int i = 0; i < 4; ++i) {
        xv[i] = xr[tid + i * 256];
        ss += xv[i].x * xv[i].x + xv[i].y * xv[i].y
            + xv[i].z * xv[i].z + xv[i].w * xv[i].w;
    }
#pragma unroll
    for (int off = 32; off; off >>= 1) ss += __shfl_xor(ss, off);
    if ((tid & 63) == 0) red[tid >> 6] = ss;
    __syncthreads();
    const float tot = red[0] + red[1] + red[2] + red[3];
    const float sc = 1.f / sqrtf(tot * (1.f / (float)H_) + 1e-6f);
    const float4* wr = (const float4*)w;
    int* ob = (int*)out;
    const long rb = row >> 7;
    const int rr = (int)(row & 127);
#pragma unroll
    for (int i = 0; i < 4; ++i) {
        const float4 wv = wr[tid + i * 256];
        const int b0 = (int)fminf(fmaxf(rintf(xv[i].x * sc * wv.x), -128.f), 127.f);
        const int b1 = (int)fminf(fmaxf(rintf(xv[i].y * sc * wv.y), -128.f), 127.f);
        const int b2 = (int)fminf(fmaxf(rintf(xv[i].z * sc * wv.z), -128.f), 127.f);
        const int b3 = (int)fminf(fmaxf(rintf(xv[i].w * sc * wv.w), -128.f), 127.f);
        const int packed = (b0 & 255) | ((b1 & 255) << 8) | ((b2 & 255) << 16) | (b3 << 24);
        const int j4 = tid + i * 256;              // int32 group within row
        const long a32 = ((rb * 64 + (j4 >> 4)) << 11) + (((j4 >> 2) & 3) << 9)
                       + (rr << 2) + (j4 & 3);
        ob[a32] = packed;
    }
}

// ---------------------------------------------------------------------------
// int8 GEMM on tiled-i8 A and W. BK=128 double-step, depth-2 ring, counted
// vmcnt(8) (never 0 mid-loop), round-5-validated sync structure:
// {issue next 16KB units -> vmcnt(8) -> barrier -> 2x[8 ds_read + 16 MFMA]
//  -> barrier}. 64KB LDS -> 2 blocks/CU.
// MODE 0: C = acc*s + bias (+residual), fp32 row-major.
// MODE 1: u = acc*s + bias; a = silu(g)*u; out8 = quant(a/qscale), tiled-i8.
template<int MODE>
__global__ __launch_bounds__(256, 2)
void gemm_i8t(const signed char* __restrict__ A8, const signed char* __restrict__ W8,
              const float* __restrict__ scale_ptr, const float* __restrict__ bias,
              const float* __restrict__ residual, float* __restrict__ C,
              const float* __restrict__ gbuf, const float* __restrict__ qscale,
              signed char* __restrict__ out8,
              const int N, const int K, const int gx)
{
    __shared__ __align__(16) signed char lsA[2][16384];
    __shared__ __align__(16) signed char lsB[2][16384];

    int bid = blockIdx.x;
    {   // bijective XCD chunked remap (m204)
        const int nwg = gridDim.x;
        const int q = nwg >> 3, r = nwg & 7;
        const int xcd = bid & 7, idx = bid >> 3;
        bid = (xcd < r) ? (xcd * (q + 1) + idx)
                        : (r * (q + 1) + (xcd - r) * q + idx);
    }
    const int bx = bid % gx, by = bid / gx;

    const int tid  = threadIdx.x;
    const int lane = tid & 63, wid = tid >> 6;
    const int bm = bx << 7, bn = by << 7;
    const int wm = (wid >> 1) << 6, wn = (wid & 1) << 6;

    i32x4 acc[4][4];
#pragma unroll
    for (int m = 0; m < 4; ++m)
#pragma unroll
        for (int n = 0; n < 4; ++n) acc[m][n] = (i32x4){0, 0, 0, 0};

    const int nk  = K >> 6;                        // 64-k tiles
    const int nk2 = K >> 7;                        // 128-k double steps
    const signed char* abase = A8 + ((long)bx * nk << 13);
    const signed char* bbase = W8 + ((long)by * nk << 13);
    const int sgg = wid * 4096 + lane * 16;        // GLOBAL src: per-lane
    const int sgl = wid * 4096;                    // LDS dest: wave-uniform

    // prologue: stage step 0 (16KB A + 16KB B; 8 gloads/wave)
#pragma unroll
    for (int c = 0; c < 4; ++c) {
        gload_lds16(abase + sgg + c * 1024, lsA[0] + sgl + c * 1024);
        gload_lds16(bbase + sgg + c * 1024, lsB[0] + sgl + c * 1024);
    }

    for (int kt = 0; kt < nk2; ++kt) {
        const int cur = kt & 1, nxt = cur ^ 1;
        if (kt + 1 < nk2) {                        // issue step kt+1 into nxt
            const signed char* at = abase + ((long)(kt + 1) << 14);
            const signed char* bt = bbase + ((long)(kt + 1) << 14);
#pragma unroll
            for (int c = 0; c < 4; ++c) {
                gload_lds16(at + sgg + c * 1024, lsA[nxt] + sgl + c * 1024);
                gload_lds16(bt + sgg + c * 1024, lsB[nxt] + sgl + c * 1024);
            }
            // wait ONLY step kt's 8 loads; step kt+1's 8 stay in flight (T4)
            asm volatile("s_waitcnt vmcnt(8)" ::: "memory");
        } else {
            asm volatile("s_waitcnt vmcnt(0)" ::: "memory");
        }
        __builtin_amdgcn_s_barrier();              // step kt visible to all

        const int kg = (lane >> 4) * 2048, fr = (lane & 15) * 16;
#pragma unroll
        for (int s = 0; s < 2; ++s) {              // two 64-k sub-steps
            const int off = s * 8192;
            i32x4 af[4], bf[4];
#pragma unroll
            for (int m = 0; m < 4; ++m)
                af[m] = *(const i32x4*)(lsA[cur] + off + kg + wm * 16 + m * 256 + fr);
#pragma unroll
            for (int n = 0; n < 4; ++n)
                bf[n] = *(const i32x4*)(lsB[cur] + off + kg + wn * 16 + n * 256 + fr);
            __builtin_amdgcn_s_setprio(1);
#pragma unroll
            for (int m = 0; m < 4; ++m)
#pragma unroll
                for (int n = 0; n < 4; ++n)
                    acc[m][n] = __builtin_amdgcn_mfma_i32_16x16x64_i8(af[m], bf[n], acc[m][n], 0, 0, 0);
            __builtin_amdgcn_s_setprio(0);
        }
        __builtin_amdgcn_s_barrier();              // buf[cur] free for reuse
    }

    const float s = *scale_ptr;
    const int rq = (lane >> 4) * 4, fc = lane & 15;
    if (MODE == 0) {
#pragma unroll
        for (int m = 0; m < 4; ++m) {
#pragma unroll
            for (int n = 0; n < 4; ++n) {
                const int col = bn + wn + n * 16 + fc;
                const float bcol = bias[col];
#pragma unroll
                for (int r = 0; r < 4; ++r) {
                    const int row = bm + wm + m * 16 + rq + r;
                    float v = (float)acc[m][n][r] * s + bcol;
                    if (residual) v += residual[(long)row * N + col];
                    C[(long)row * N + col] = v;
                }
            }
        }
    } else {
        const float dinv = 1.f / qscale[0];
        const int nko = N >> 6;                    // out tiling over N (=I)
#pragma unroll
        for (int m = 0; m < 4; ++m) {
#pragma unroll
            for (int n = 0; n < 4; ++n) {
                const int col = bn + wn + n * 16 + fc;
                const float bcol = bias[col];
                const int ktc = col >> 6, kgc = (col >> 4) & 3, jc = col & 15;
#pragma unroll
                for (int r = 0; r < 4; ++r) {
                    const int row = bm + wm + m * 16 + rq + r;
                    const float u = (float)acc[m][n][r] * s + bcol;
                    const float g = gbuf[(long)row * N + col];
                    const float a = g / (1.f + __expf(-g)) * u;
                    const float qv = fminf(fmaxf(rintf(a * dinv), -128.f), 127.f);
                    const long addr = (((long)(row >> 7) * nko + ktc) << 13)
                                    + (kgc << 11) + ((row & 127) << 4) + jc;
                    out8[addr] = (signed char)(int)qv;
                }
            }
        }
    }
}

// ---------------------------------------------------------------------------
// RoPE applied in-place to q and k, layout [B,S,NH,HD] == [B,S,H] h-major.
__global__ __launch_bounds__(256)
void rope_k(float* __restrict__ q, float* __restrict__ k)
{
    const int row = blockIdx.x;            // token index b*S+s
    const int s = row & (S_ - 1);
    float* qr = q + (long)row * H_;
    float* kr = k + (long)row * H_;
    for (int t = threadIdx.x; t < NH_ * 64; t += 256) {
        const int nh = t >> 6, i = t & 63;
        const float inv = powf(10000.f, -(float)(2 * i) * (1.f / 128.f));
        const float f = (float)s * inv;
        float sn, c;
        sincosf(f, &sn, &c);
        const int base = nh * 128 + i;
        const float q0 = qr[base], q1 = qr[base + 64];
        qr[base]      = q0 * c - q1 * sn;
        qr[base + 64] = q1 * c + q0 * sn;
        const float k0 = kr[base], k1 = kr[base + 64];
        kr[base]      = k0 * c - k1 * sn;
        kr[base + 64] = k1 * c + k0 * sn;
    }
}

// ---------------------------------------------------------------------------
// Flash attention, bf16 MFMA; epilogue fuses o/o_in_scale quant -> tiled-i8.
__global__ __launch_bounds__(256, 2)
void attn_mfma_k(const float* __restrict__ q, const float* __restrict__ k,
                 const float* __restrict__ v, signed char* __restrict__ out8,
                 const float* __restrict__ osc)
{
    __shared__ __align__(16) char lsK[8192];        // [32 krow][128 d] bf16, XOR swizzle
    __shared__ __align__(16) char lsV[10240];       // V^T [128 d][40 pitch] bf16
    __shared__ __align__(16) char lsP[4][1024];     // per-wave P [16][32] bf16, XOR swizzle

    const int tid = threadIdx.x, lane = tid & 63, wid = tid >> 6;
    const int bid = blockIdx.x;
    const int qt = 15 - (bid >> 6);                 // reversed: long blocks first
    const int bh = bid & 63;
    const int b = bh >> 5, h = bh & 31;
    const int q0 = qt * 64;
    const int qw = q0 + wid * 16;                   // this wave's first q row

    const float* qbase = q + (long)(b * S_) * H_ + (long)h * HD_;
    const float* kbase = k + (long)(b * S_) * H_ + (long)h * HD_;
    const float* vbase = v + (long)(b * S_) * H_ + (long)h * HD_;

    const int frow = lane & 15, fgrp = lane >> 4;
    const float sc = 0.08838834764831845f;          // 1/sqrt(128), folded into Q

    bf16x8 qf[4];
    {
        const float* qr = qbase + (long)(qw + frow) * H_;
#pragma unroll
        for (int c = 0; c < 4; ++c) {
            const float4 a = *(const float4*)(qr + c * 32 + fgrp * 8);
            const float4 bq = *(const float4*)(qr + c * 32 + fgrp * 8 + 4);
            bf16x8 t;
            t[0] = (short)f2bf(a.x * sc);  t[1] = (short)f2bf(a.y * sc);
            t[2] = (short)f2bf(a.z * sc);  t[3] = (short)f2bf(a.w * sc);
            t[4] = (short)f2bf(bq.x * sc); t[5] = (short)f2bf(bq.y * sc);
            t[6] = (short)f2bf(bq.z * sc); t[7] = (short)f2bf(bq.w * sc);
            qf[c] = t;
        }
    }

    f32x4 oacc[8];
#pragma unroll
    for (int n2 = 0; n2 < 8; ++n2) oacc[n2] = (f32x4){0.f, 0.f, 0.f, 0.f};
    float mr[4] = {-1e30f, -1e30f, -1e30f, -1e30f};
    float lr[4] = {0.f, 0.f, 0.f, 0.f};

    const int nt = (q0 >> 5) + 2;
    for (int kt = 0; kt < nt; ++kt) {
        if (kt) __syncthreads();
        {
            const float* kg = kbase + (long)(kt * 32) * H_;
            const float* vg = vbase + (long)(kt * 32) * H_;
#pragma unroll
            for (int i = 0; i < 4; ++i) {
                const int lin = i * 256 + tid;
                const int kr = lin >> 5;
                const int d4 = (lin & 31) * 4;
                const float4 kv = *(const float4*)(kg + (long)kr * H_ + d4);
                const float4 vv = *(const float4*)(vg + (long)kr * H_ + d4);
                ushort4 kb;
                kb.x = f2bf(kv.x); kb.y = f2bf(kv.y); kb.z = f2bf(kv.z); kb.w = f2bf(kv.w);
                *(ushort4*)(lsK + kr * 256 + ((d4 * 2) ^ ((kr & 7) << 4))) = kb;
                *(unsigned short*)(lsV + (d4 + 0) * 80 + kr * 2) = f2bf(vv.x);
                *(unsigned short*)(lsV + (d4 + 1) * 80 + kr * 2) = f2bf(vv.y);
                *(unsigned short*)(lsV + (d4 + 2) * 80 + kr * 2) = f2bf(vv.z);
                *(unsigned short*)(lsV + (d4 + 3) * 80 + kr * 2) = f2bf(vv.w);
            }
        }
        __syncthreads();

        if (kt * 32 <= qw + 15) {
            f32x4 s0 = (f32x4){0.f, 0.f, 0.f, 0.f};
            f32x4 s1 = (f32x4){0.f, 0.f, 0.f, 0.f};
            const int swz = (frow & 7) << 4;
#pragma unroll
            for (int c = 0; c < 4; ++c) {
                const int dby = c * 64 + fgrp * 16;
                const bf16x8 kfA = *(const bf16x8*)(lsK + frow * 256 + (dby ^ swz));
                const bf16x8 kfB = *(const bf16x8*)(lsK + (frow + 16) * 256 + (dby ^ swz));
                s0 = __builtin_amdgcn_mfma_f32_16x16x32_bf16(qf[c], kfA, s0, 0, 0, 0);
                s1 = __builtin_amdgcn_mfma_f32_16x16x32_bf16(qf[c], kfB, s1, 0, 0, 0);
            }

            const int colg0 = kt * 32 + frow;
            float cf[4];
#pragma unroll
            for (int r = 0; r < 4; ++r) {
                const int rowg = qw + fgrp * 4 + r;
                const float a0 = (colg0 <= rowg) ? s0[r] : -1e30f;
                const float a1 = (colg0 + 16 <= rowg) ? s1[r] : -1e30f;
                float mx = fmaxf(a0, a1);
#pragma unroll
                for (int off2 = 1; off2 < 16; off2 <<= 1) mx = fmaxf(mx, __shfl_xor(mx, off2));
                const float mnew = fmaxf(mr[r], mx);
                cf[r] = __expf(mr[r] - mnew);
                mr[r] = mnew;
                const float p0 = __expf(a0 - mnew);
                const float p1 = __expf(a1 - mnew);
                float sm = p0 + p1;
#pragma unroll
                for (int off2 = 1; off2 < 16; off2 <<= 1) sm += __shfl_xor(sm, off2);
                lr[r] = lr[r] * cf[r] + sm;
                const int row = fgrp * 4 + r;
                const int psw = (row & 3) << 4;
                *(unsigned short*)(lsP[wid] + row * 64 + ((frow * 2) ^ psw)) = f2bf(p0);
                *(unsigned short*)(lsP[wid] + row * 64 + (((16 + frow) * 2) ^ psw)) = f2bf(p1);
            }
#pragma unroll
            for (int n2 = 0; n2 < 8; ++n2) {
#pragma unroll
                for (int r = 0; r < 4; ++r) oacc[n2][r] *= cf[r];
            }
            const bf16x8 pf = *(const bf16x8*)(lsP[wid] + frow * 64 + ((fgrp * 16) ^ ((frow & 3) << 4)));
#pragma unroll
            for (int n2 = 0; n2 < 8; ++n2) {
                const bf16x8 vf = *(const bf16x8*)(lsV + (n2 * 16 + frow) * 80 + fgrp * 16);
                oacc[n2] = __builtin_amdgcn_mfma_f32_16x16x32_bf16(pf, vf, oacc[n2], 0, 0, 0);
            }
        }
    }

    // epilogue: o = oacc/l, q8 = clip(rint(o/osc)) -> tiled-i8 (nk = 64)
    const float oinv = 1.f / osc[0];
    float inv[4];
#pragma unroll
    for (int r = 0; r < 4; ++r) inv[r] = 1.f / lr[r];
#pragma unroll
    for (int n2 = 0; n2 < 8; ++n2) {
        const int kk = h * 128 + n2 * 16 + frow;
        const int ktc = kk >> 6, kgc = (kk >> 4) & 3, jc = kk & 15;
#pragma unroll
        for (int r = 0; r < 4; ++r) {
            const int rowt = b * S_ + qw + fgrp * 4 + r;
            const float ov = oacc[n2][r] * inv[r];
            const float qv = fminf(fmaxf(rintf(ov * oinv), -128.f), 127.f);
            const long addr = (((long)(rowt >> 7) * 64 + ktc) << 13)
                            + (kgc << 11) + ((rowt & 127) << 4) + jc;
            out8[addr] = (signed char)(int)qv;
        }
    }
}

// ---------------------------------------------------------------------------
extern "C" void kernel_launch(void* const* d_in, const int* in_sizes, int n_in,
                              void* d_out, int out_size, void* d_ws, size_t ws_size,
                              hipStream_t stream)
{
    const float* hidden = (const float*)d_in[0];
    const float* ln1 = (const float*)d_in[1];
    const float* ln2 = (const float*)d_in[2];
    const int* Wq = (const int*)d_in[3];
    const int* Wk = (const int*)d_in[4];
    const int* Wv = (const int*)d_in[5];
    const int* Wo = (const int*)d_in[6];
    const int* Wg = (const int*)d_in[7];
    const int* Wu = (const int*)d_in[8];
    const int* Wd = (const int*)d_in[9];
    const float* bq = (const float*)d_in[10];
    const float* bk = (const float*)d_in[11];
    const float* bv = (const float*)d_in[12];
    const float* bo = (const float*)d_in[13];
    const float* bg = (const float*)d_in[14];
    const float* bu = (const float*)d_in[15];
    const float* bd = (const float*)d_in[16];
    const float* sq = (const float*)d_in[17];
    const float* sk = (const float*)d_in[18];
    const float* sv = (const float*)d_in[19];
    const float* so = (const float*)d_in[20];
    const float* sg = (const float*)d_in[21];
    const float* su = (const float*)d_in[22];
    const float* sd = (const float*)d_in[23];
    const float* o_sc = (const float*)d_in[24];
    const float* d_sc = (const float*)d_in[25];

    // workspace (MiB offsets, peak 206 MiB):
    //  [0,22)    A8 tiled int8: hq / oq / hq2 (8 MiB each, sequential reuse)
    //  [22,66)   WP: packed-W scratch (max 43.01 MiB)
    //  [66,98)   Qb fp32 -> (post-attn) Hb
    //  [98,130)  Kb ; [130,162) Vb ; [98,184) Gb (after attn, K/V dead)
    //  [184,206) AQ8 tiled int8 (2048 x 11008)
    char* ws = (char*)d_ws;
    signed char* HQ8 = (signed char*)ws;
    signed char* WP  = (signed char*)(ws + ((size_t)22 << 20));
    float* Qb = (float*)(ws + ((size_t)66 << 20));
    float* Kb = (float*)(ws + ((size_t)98 << 20));
    float* Vb = (float*)(ws + ((size_t)130 << 20));
    float* Gb = (float*)(ws + ((size_t)98 << 20));
    signed char* AQ8 = (signed char*)(ws + ((size_t)184 << 20));
    float* Hb = Qb;
    float* out = (float*)d_out;

    const dim3 blk(256);
    const int gxH = R_ / 128;                 // 16 row blocks
    const int nwgH = gxH * (H_ / 128);        // 512
    const int nwgI = gxH * (I_ / 128);        // 1376
    const dim3 gpH(H_ / 64, H_ / 128);        // pack grids: (nk, N/128)
    const dim3 gpI(H_ / 64, I_ / 128);
    const dim3 gpD(I_ / 64, H_ / 128);

    rmsnorm_quant_k<<<R_, blk, 0, stream>>>(hidden, ln1, HQ8);

    packW_k<<<gpH, blk, 0, stream>>>(Wq, WP, H_);
    gemm_i8t<0><<<nwgH, blk, 0, stream>>>(HQ8, WP, sq, bq, nullptr, Qb,
                                          nullptr, nullptr, nullptr, H_, H_, gxH);
    packW_k<<<gpH, blk, 0, stream>>>(Wk, WP, H_);
    gemm_i8t<0><<<nwgH, blk, 0, stream>>>(HQ8, WP, sk, bk, nullptr, Kb,
                                          nullptr, nullptr, nullptr, H_, H_, gxH);
    packW_k<<<gpH, blk, 0, stream>>>(Wv, WP, H_);
    gemm_i8t<0><<<nwgH, blk, 0, stream>>>(HQ8, WP, sv, bv, nullptr, Vb,
                                          nullptr, nullptr, nullptr, H_, H_, gxH);

    rope_k<<<R_, blk, 0, stream>>>(Qb, Kb);
    attn_mfma_k<<<B_ * NH_ * (S_ / 64), blk, 0, stream>>>(Qb, Kb, Vb, HQ8, o_sc);

    packW_k<<<gpH, blk, 0, stream>>>(Wo, WP, H_);
    gemm_i8t<0><<<nwgH, blk, 0, stream>>>(HQ8, WP, so, bo, hidden, Hb,
                                          nullptr, nullptr, nullptr, H_, H_, gxH);

    rmsnorm_quant_k<<<R_, blk, 0, stream>>>(Hb, ln2, HQ8);

    packW_k<<<gpI, blk, 0, stream>>>(Wg, WP, H_);
    gemm_i8t<0><<<nwgI, blk, 0, stream>>>(HQ8, WP, sg, bg, nullptr, Gb,
                                          nullptr, nullptr, nullptr, I_, H_, gxH);
    packW_k<<<gpI, blk, 0, stream>>>(Wu, WP, H_);
    gemm_i8t<1><<<nwgI, blk, 0, stream>>>(HQ8, WP, su, bu, nullptr, nullptr,
                                          Gb, d_sc, AQ8, I_, H_, gxH);
    packW_k<<<gpD, blk, 0, stream>>>(Wd, WP, I_);
    gemm_i8t<0><<<nwgH, blk, 0, stream>>>(AQ8, WP, sd, bd, Hb, out,
                                          nullptr, nullptr, nullptr, H_, I_, gxH);
}